// Round 12
// baseline (239.768 us; speedup 1.0000x reference)
//
#include <hip/hip_runtime.h>
#include <math.h>
#include <stdint.h>

#define TOKENS 8192
#define DIM 1024
#define N3 3072
#define NSEQ 2048
#define NH 16
#define DH 64

typedef __attribute__((ext_vector_type(8))) __bf16 bf16x8;
typedef __attribute__((ext_vector_type(4))) float f32x4;
typedef __attribute__((ext_vector_type(16))) float f32x16;
typedef __attribute__((ext_vector_type(4))) short short4v;

// hardware bf16 convert (RNE) — no builtin on gfx950, inline asm per T12/m240
__device__ __forceinline__ unsigned cvt2bf(float a, float b) {
    unsigned r;
    asm("v_cvt_pk_bf16_f32 %0, %1, %2" : "=v"(r) : "v"(a), "v"(b));
    return r;
}
__device__ __forceinline__ unsigned short f2bf(float f) {
    unsigned r;
    asm("v_cvt_pk_bf16_f32 %0, %1, %1" : "=v"(r) : "v"(f));
    return (unsigned short)r;
}
// raw v_exp_f32 (2^x); safe for finite x
__device__ __forceinline__ float exp2_raw(float x) {
    float r;
    asm("v_exp_f32 %0, %1" : "=v"(r) : "v"(x));
    return r;
}

__device__ __forceinline__ void glds16(const void* g, void* l) {
    __builtin_amdgcn_global_load_lds((__attribute__((address_space(1))) void*)(void*)g,
                                     (__attribute__((address_space(3))) void*)l, 16, 0, 0);
}

// ---------------- transpose f32 [R][C] -> bf16 [C][R] ----------------
__global__ __launch_bounds__(256) void transpose_to_bf16(
    const float* __restrict__ in, unsigned short* __restrict__ out, int R, int C) {
    __shared__ float tile[64][65];
    int n0 = blockIdx.x * 64, k0 = blockIdx.y * 64;
    int t = threadIdx.x;
#pragma unroll
    for (int i = 0; i < 16; i++) {
        int idx = i * 256 + t;
        int r = idx >> 6, c = idx & 63;
        tile[r][c] = in[(size_t)(k0 + r) * C + n0 + c];
    }
    __syncthreads();
#pragma unroll
    for (int i = 0; i < 16; i++) {
        int idx = i * 256 + t;
        int r = idx >> 6, c = idx & 63;
        out[(size_t)(n0 + r) * R + k0 + c] = f2bf(tile[c][r]);
    }
}

// ---------------- LayerNorm: f32 [8192][1024] -> bf16 ----------------
__global__ __launch_bounds__(256) void ln_kernel(
    const float* __restrict__ x, const float* __restrict__ gamma,
    const float* __restrict__ beta, unsigned short* __restrict__ xn) {
    int row = blockIdx.x;
    int t = threadIdx.x;
    const float4 v = ((const float4*)(x + (size_t)row * DIM))[t];
    float s = v.x + v.y + v.z + v.w;
    float sq = v.x * v.x + v.y * v.y + v.z * v.z + v.w * v.w;
#pragma unroll
    for (int m = 1; m < 64; m <<= 1) {
        s += __shfl_xor(s, m);
        sq += __shfl_xor(sq, m);
    }
    __shared__ float ws[4], wq[4];
    int w = t >> 6, lane = t & 63;
    if (lane == 0) { ws[w] = s; wq[w] = sq; }
    __syncthreads();
    s = ws[0] + ws[1] + ws[2] + ws[3];
    sq = wq[0] + wq[1] + wq[2] + wq[3];
    float mu = s * (1.0f / DIM);
    float var = sq * (1.0f / DIM) - mu * mu;
    float rstd = rsqrtf(var + 1e-5f);
    const float4 g = ((const float4*)gamma)[t];
    const float4 bb = ((const float4*)beta)[t];
    uint2 o;
    o.x = cvt2bf((v.x - mu) * rstd * g.x + bb.x, (v.y - mu) * rstd * g.y + bb.y);
    o.y = cvt2bf((v.z - mu) * rstd * g.z + bb.z, (v.w - mu) * rstd * g.w + bb.w);
    *(uint2*)(xn + (size_t)row * DIM + t * 4) = o;
}

// XCD-aware bijective swizzle of the linear workgroup id (nwg % 8 == 0)
__device__ __forceinline__ void xcd_swizzle(int& bx, int& by) {
    int nwgx = gridDim.x;
    int nwg = nwgx * gridDim.y;
    int wg = by * nwgx + bx;
    int cpx = nwg >> 3;
    int swz = (wg & 7) * cpx + (wg >> 3);
    bx = swz % nwgx;
    by = swz / nwgx;
}

// ---------------- shared GEMM core: counted-vmcnt pipeline + FRAGMENT-ORDERED LDS ----------------
// C[128x128] = A[M,K] * Bt[N,K]^T. 4 waves. 3 tile-buffers, 2-deep prefetch, one barrier
// per K-step, counted vmcnt only (round-9 pipeline). NEW (round-12): LDS is fragment-
// ordered — chunk c (1KB) holds MFMA fragment c (64 lanes x 16B contiguous), staged via
// per-lane pre-permuted GLOBAL source (gload_lds LDS dest stays lane-linear). Frag reads
// are chunk*1024 + lane*16 -> ZERO bank conflicts (was 8-way, 6.29M cycles/dispatch).
// A-frag c: row brow+c*16+(lane&15), k k0+(lane>>4)*8 — same element->lane map as MFMA.
// SPILL-FREE REQUIRED (scratch ops share vmcnt).
__device__ __forceinline__ void gemm_stage(
    const unsigned short* __restrict__ A, const unsigned short* __restrict__ Bt, int K,
    int brow, int bcol, int k0, char* Abuf, char* Bbuf, int w, int r15, int khi) {
#pragma unroll
    for (int i = 0; i < 2; i++) {
        int c = 2 * w + i;  // wave w stages A-chunks {2w,2w+1} and B-chunks {2w,2w+1}
        glds16(A + (size_t)(brow + c * 16 + r15) * K + k0 + khi, Abuf + c * 1024);
        glds16(Bt + (size_t)(bcol + c * 16 + r15) * K + k0 + khi, Bbuf + c * 1024);
    }
}

__device__ __forceinline__ void gemm_core(
    const unsigned short* __restrict__ A, const unsigned short* __restrict__ Bt, int K,
    int brow, int bcol, char* As, char* Bs, f32x4 acc[4][4]) {
    int t = threadIdx.x, w = t >> 6, lane = t & 63;
    int wr = w >> 1, wc = w & 1;
    int r15 = lane & 15, khi = (lane >> 4) * 8;
    char* a0 = As; char* a1 = As + 8192; char* a2 = As + 16384;
    char* b0 = Bs; char* b1 = Bs + 8192; char* b2 = Bs + 16384;
    gemm_stage(A, Bt, K, brow, bcol, 0, a0, b0, w, r15, khi);
    gemm_stage(A, Bt, K, brow, bcol, 32, a1, b1, w, r15, khi);
    int NT = K >> 5;
    for (int kt = 0; kt < NT; kt++) {
        asm volatile("s_waitcnt vmcnt(4)" ::: "memory");  // tile kt's 4 loads landed (per-wave)
        __builtin_amdgcn_s_barrier();                     // all waves have tile kt; buf2 free
        int kn = kt + 2; if (kn >= NT) kn -= NT;          // wrap-reload at tail: harmless
        gemm_stage(A, Bt, K, brow, bcol, kn << 5, a2, b2, w, r15, khi);
        bf16x8 a[4], b[4];
#pragma unroll
        for (int i = 0; i < 4; i++) {
            a[i] = *(const bf16x8*)(a0 + (wr * 4 + i) * 1024 + lane * 16);
            b[i] = *(const bf16x8*)(b0 + (wc * 4 + i) * 1024 + lane * 16);
        }
        __builtin_amdgcn_s_setprio(1);
#pragma unroll
        for (int i = 0; i < 4; i++)
#pragma unroll
            for (int j = 0; j < 4; j++)
                acc[i][j] = __builtin_amdgcn_mfma_f32_16x16x32_bf16(a[i], b[j], acc[i][j], 0, 0, 0);
        __builtin_amdgcn_s_setprio(0);
        char* tp;
        tp = a0; a0 = a1; a1 = a2; a2 = tp;
        tp = b0; b0 = b1; b1 = b2; b2 = tp;
    }
}

// QKV GEMM: xn[8192][1024] @ w_qkv -> writes Q (scaled), K, V^T in [b,h,...] layouts
#define QSCALE_LOG2E 0.18033688011112042f  // (1/sqrt(64)) * log2(e)

__global__ __launch_bounds__(256) void gemm_qkv(
    const unsigned short* __restrict__ A, const unsigned short* __restrict__ Bt,
    unsigned short* __restrict__ Qb, unsigned short* __restrict__ Kb,
    unsigned short* __restrict__ Vt) {
    __shared__ __align__(16) char As[3 * 8192];
    __shared__ __align__(16) char Bs[3 * 8192];
    int bx = blockIdx.x, by = blockIdx.y;
    xcd_swizzle(bx, by);
    int brow = by * 128, bcol = bx * 128;
    f32x4 acc[4][4] = {};
    gemm_core(A, Bt, DIM, brow, bcol, As, Bs, acc);

    int t = threadIdx.x, w = t >> 6, lane = t & 63;
    int wr = w >> 1, wc = w & 1;
    int part = bcol >> 10;  // uniform per block: 0=q 1=k 2=v
#pragma unroll
    for (int i = 0; i < 4; i++) {
#pragma unroll
        for (int j = 0; j < 4; j++) {
            int col = bcol + wc * 64 + j * 16 + (lane & 15);
            int within = col & 1023;
            int h = within >> 6, d = within & 63;
            int rowb = brow + wr * 64 + i * 16 + (lane >> 4) * 4;
            if (part == 2) {
                // V^T: n consecutive over r -> pack 4
                int b = rowb >> 11, n = rowb & 2047;
                int bh = (b << 4) + h;
                uint2 pv;
                pv.x = cvt2bf(acc[i][j][0], acc[i][j][1]);
                pv.y = cvt2bf(acc[i][j][2], acc[i][j][3]);
                *(uint2*)(Vt + ((size_t)bh * 64 + d) * 2048 + n) = pv;
            } else {
#pragma unroll
                for (int r = 0; r < 4; r++) {
                    int row = rowb + r;
                    int b = row >> 11, n = row & 2047;
                    int bh = (b << 4) + h;
                    float val = acc[i][j][r];
                    if (part == 0)
                        Qb[((size_t)bh * 2048 + n) * 64 + d] = f2bf(val * QSCALE_LOG2E);
                    else
                        Kb[((size_t)bh * 2048 + n) * 64 + d] = f2bf(val);
                }
            }
        }
    }
}

// out GEMM: att[8192][1024] @ w_out + b_out -> f32 out
__global__ __launch_bounds__(256) void gemm_out(
    const unsigned short* __restrict__ A, const unsigned short* __restrict__ Bt,
    const float* __restrict__ bias, float* __restrict__ out) {
    __shared__ __align__(16) char As[3 * 8192];
    __shared__ __align__(16) char Bs[3 * 8192];
    int bx = blockIdx.x, by = blockIdx.y;
    xcd_swizzle(bx, by);
    int brow = by * 128, bcol = bx * 128;
    f32x4 acc[4][4] = {};
    gemm_core(A, Bt, DIM, brow, bcol, As, Bs, acc);

    int t = threadIdx.x, w = t >> 6, lane = t & 63;
    int wr = w >> 1, wc = w & 1;
#pragma unroll
    for (int i = 0; i < 4; i++) {
#pragma unroll
        for (int j = 0; j < 4; j++) {
            int col = bcol + wc * 64 + j * 16 + (lane & 15);
            float bv = bias[col];
#pragma unroll
            for (int r = 0; r < 4; r++) {
                int row = brow + wr * 64 + i * 16 + (lane >> 4) * 4 + r;
                out[(size_t)row * DIM + col] = acc[i][j][r] + bv;
            }
        }
    }
}

// ---------------- flash attention v7: no-max softmax (round-11, unchanged) ----------------
__global__ __launch_bounds__(512, 4) void attn_kernel(
    const unsigned short* __restrict__ Qb, const unsigned short* __restrict__ Kb,
    const unsigned short* __restrict__ Vt, const float* __restrict__ pos,
    unsigned short* __restrict__ att) {
    __shared__ __align__(16) char Ks[4][8192];
    __shared__ __align__(16) char Vs[4][8192];
    int t = threadIdx.x, w = t >> 6, lane = t & 63;
    int l31 = lane & 31, lhi = lane >> 5;

    // XCD head-grouping: all q-tiles of head-batch bh land on XCD bh%8
    int L = blockIdx.y * gridDim.x + blockIdx.x;      // 0..511
    int bh = (L & 7) + (((L >> 3) & 7) << 3);         // head-batch index 0..63
    int qt = L >> 6;                                  // q-tile 0..7
    int b = bh >> 4, h = bh & 15;
    int qr = qt * 256 + w * 32 + l31;                 // this lane's q row

    const unsigned short* Qh = Qb + (size_t)bh * NSEQ * DH;
    const char* Khc = (const char*)(Kb + (size_t)bh * NSEQ * DH);
    const char* Vhc = (const char*)(Vt + (size_t)bh * DH * NSEQ);

    // Q fragments: qf[ks] = Q[qr][ks*16 + lhi*8 .. +8]
    bf16x8 qf[4];
#pragma unroll
    for (int ks = 0; ks < 4; ks++)
        qf[ks] = *(const bf16x8*)(Qh + (size_t)qr * DH + ks * 16 + lhi * 8);

    f32x16 oacc[2] = {};
    float lsum = 0.f;  // per-lane partial (pair-combined at epilogue)

    // fragment-ordered cooperative stage: wave w supplies chunk c=w (1 K + 1 V load)
    int ct = w >> 2, cs = w & 3;
    const char* Ksrc = Khc + (size_t)(ct * 32 + l31) * 128 + cs * 32 + lhi * 16;
    const char* Vsrc = Vhc + (size_t)(ct * 32 + l31) * 4096 + (size_t)(cs * 16 + lhi * 8) * 2;
    auto stage = [&](char* kbuf, char* vbuf, int kv0) {
        glds16(Ksrc + (size_t)kv0 * 128, kbuf + w * 1024);
        glds16(Vsrc + (size_t)kv0 * 2, vbuf + w * 1024);
    };

    // one KV-tile compute: QK^T -> P=exp2(S) -> PV
    auto compute = [&](const char* kc, const char* vc) {
        f32x16 st0 = {}, st1 = {};
        __builtin_amdgcn_s_setprio(1);
#pragma unroll
        for (int ks = 0; ks < 4; ks++) {
            bf16x8 kf = *(const bf16x8*)(kc + ks * 1024 + lane * 16);
            st0 = __builtin_amdgcn_mfma_f32_32x32x16_bf16(kf, qf[ks], st0, 0, 0, 0);
        }
#pragma unroll
        for (int ks = 0; ks < 4; ks++) {
            bf16x8 kf = *(const bf16x8*)(kc + (4 + ks) * 1024 + lane * 16);
            st1 = __builtin_amdgcn_mfma_f32_32x32x16_bf16(kf, qf[ks], st1, 0, 0, 0);
        }
        __builtin_amdgcn_s_setprio(0);

        // P = exp2(S) in place (no max subtraction); 4-way partial row-sum
        {
            float s0 = 0.f, s1 = 0.f, s2 = 0.f, s3 = 0.f;
#pragma unroll
            for (int r = 0; r < 16; r += 4) {
                float e0 = exp2_raw(st0[r]);
                float e1 = exp2_raw(st0[r + 1]);
                float e2 = exp2_raw(st0[r + 2]);
                float e3 = exp2_raw(st0[r + 3]);
                st0[r] = e0; st0[r + 1] = e1; st0[r + 2] = e2; st0[r + 3] = e3;
                s0 += e0; s1 += e1; s2 += e2; s3 += e3;
            }
#pragma unroll
            for (int r = 0; r < 16; r += 4) {
                float e0 = exp2_raw(st1[r]);
                float e1 = exp2_raw(st1[r + 1]);
                float e2 = exp2_raw(st1[r + 2]);
                float e3 = exp2_raw(st1[r + 3]);
                st1[r] = e0; st1[r + 1] = e1; st1[r + 2] = e2; st1[r + 3] = e3;
                s0 += e0; s1 += e1; s2 += e2; s3 += e3;
            }
            lsum += (s0 + s1) + (s2 + s3);
        }
        // build all 4 PV B-frags in-register (cvt_pk + permlane32_swap), then 8 PV MFMAs
        bf16x8 bfr[4];
#pragma unroll
        for (int ks = 0; ks < 4; ks++) {
            const f32x16& sv = (ks < 2) ? st0 : st1;
            int rb = (ks & 1) * 8;
            unsigned pa = cvt2bf(sv[rb + 0], sv[rb + 1]);
            unsigned pc = cvt2bf(sv[rb + 2], sv[rb + 3]);
            unsigned pb = cvt2bf(sv[rb + 4], sv[rb + 5]);
            unsigned pd = cvt2bf(sv[rb + 6], sv[rb + 7]);
            asm("v_permlane32_swap_b32 %0, %1" : "+v"(pa), "+v"(pb));
            asm("v_permlane32_swap_b32 %0, %1" : "+v"(pc), "+v"(pd));
            uint4 pw = {pa, pc, pb, pd};
            bfr[ks] = *(bf16x8*)&pw;
        }
        __builtin_amdgcn_s_setprio(1);
#pragma unroll
        for (int ks = 0; ks < 4; ks++)
#pragma unroll
            for (int dt = 0; dt < 2; dt++) {
                bf16x8 vf = *(const bf16x8*)(vc + (dt * 4 + ks) * 1024 + lane * 16);
                oacc[dt] = __builtin_amdgcn_mfma_f32_32x32x16_bf16(vf, bfr[ks], oacc[dt], 0, 0, 0);
            }
        __builtin_amdgcn_s_setprio(0);
    };

    char* kA0 = Ks[0]; char* kA1 = Ks[1]; char* kB0 = Ks[2]; char* kB1 = Ks[3];
    char* vA0 = Vs[0]; char* vA1 = Vs[1]; char* vB0 = Vs[2]; char* vB1 = Vs[3];
    stage(kA0, vA0, 0);
    stage(kA1, vA1, 64);

    for (int p = 0; p < 32; p += 2) {
        asm volatile("s_waitcnt vmcnt(2)" ::: "memory");  // tile p's K,V landed (per-wave)
        __builtin_amdgcn_s_barrier();                     // all waves have p; pair p-2 bufs free
        stage(kB0, vB0, ((p + 2) & 31) << 6);             // prefetch pair p+2 (wraps at end)
        stage(kB1, vB1, ((p + 3) & 31) << 6);
        compute(kA0, vA0);                                // tile p
        asm volatile("s_waitcnt vmcnt(4)" ::: "memory");  // tile p+1's K,V landed
        compute(kA1, vA1);                                // tile p+1 (no barrier needed)
        char* tp;
        tp = kA0; kA0 = kB0; kB0 = tp;  tp = kA1; kA1 = kB1; kB1 = tp;
        tp = vA0; vA0 = vB0; vB0 = tp;  tp = vA1; vA1 = vB1; vB1 = tp;
    }

    // epilogue: pair-combine lsum, then out[q][d] = oacc/lsum + pos, bf16
    {
        float pa = lsum, pb = lsum;
        asm("v_permlane32_swap_b32 %0, %1" : "+v"(pa), "+v"(pb));
        lsum = pa + pb;
    }
    float inv = 1.0f / lsum;
    size_t rowbase = ((size_t)b * NSEQ + qr) * DIM + h * 64;
#pragma unroll
    for (int dt = 0; dt < 2; dt++)
#pragma unroll
        for (int g4 = 0; g4 < 4; g4++) {
            int d = dt * 32 + g4 * 8 + lhi * 4;
            float4 pv = *(const float4*)(pos + rowbase + d);
            uint2 o;
            o.x = cvt2bf(oacc[dt][g4 * 4 + 0] * inv + pv.x, oacc[dt][g4 * 4 + 1] * inv + pv.y);
            o.y = cvt2bf(oacc[dt][g4 * 4 + 2] * inv + pv.z, oacc[dt][g4 * 4 + 3] * inv + pv.w);
            *(uint2*)(att + rowbase + d) = o;
        }
}

extern "C" void kernel_launch(void* const* d_in, const int* in_sizes, int n_in,
                              void* d_out, int out_size, void* d_ws, size_t ws_size,
                              hipStream_t stream) {
    const float* x = (const float*)d_in[0];
    const float* pos = (const float*)d_in[1];
    const float* w_qkv = (const float*)d_in[2];
    const float* w_out = (const float*)d_in[3];
    const float* b_out = (const float*)d_in[4];
    const float* ln_g = (const float*)d_in[5];
    const float* ln_b = (const float*)d_in[6];
    float* out = (float*)d_out;

    char* ws = (char*)d_ws;
    unsigned short* xn      = (unsigned short*)(ws);                       // 16MB (reused as att)
    unsigned short* wqkv_bt = (unsigned short*)(ws + (16ull << 20));       // 6MB
    unsigned short* wout_bt = (unsigned short*)(ws + (22ull << 20));       // 2MB
    unsigned short* Qb      = (unsigned short*)(ws + (24ull << 20));       // 16MB
    unsigned short* Kb      = (unsigned short*)(ws + (40ull << 20));       // 16MB
    unsigned short* Vt      = (unsigned short*)(ws + (56ull << 20));       // 16MB
    unsigned short* att     = xn;                                          // reuse

    transpose_to_bf16<<<dim3(N3 / 64, DIM / 64), 256, 0, stream>>>(w_qkv, wqkv_bt, DIM, N3);
    transpose_to_bf16<<<dim3(DIM / 64, DIM / 64), 256, 0, stream>>>(w_out, wout_bt, DIM, DIM);
    ln_kernel<<<TOKENS, 256, 0, stream>>>(x, ln_g, ln_b, xn);
    gemm_qkv<<<dim3(N3 / 128, TOKENS / 128), 256, 0, stream>>>(xn, wqkv_bt, Qb, Kb, Vt);
    attn_kernel<<<dim3(NSEQ / 256, 64), 512, 0, stream>>>(Qb, Kb, Vt, pos, att);
    gemm_out<<<dim3(DIM / 128, TOKENS / 128), 256, 0, stream>>>(att, wout_bt, b_out, out);
}

// Round 13
// 194.704 us; speedup vs baseline: 1.2314x; 1.2314x over previous
//
#include <hip/hip_runtime.h>
#include <math.h>
#include <stdint.h>

#define TOKENS 8192
#define DIM 1024
#define N3 3072
#define NSEQ 2048
#define NH 16
#define DH 64

typedef __attribute__((ext_vector_type(8))) __bf16 bf16x8;
typedef __attribute__((ext_vector_type(4))) float f32x4;
typedef __attribute__((ext_vector_type(16))) float f32x16;
typedef __attribute__((ext_vector_type(4))) short short4v;

// hardware bf16 convert (RNE) — no builtin on gfx950, inline asm per T12/m240
__device__ __forceinline__ unsigned cvt2bf(float a, float b) {
    unsigned r;
    asm("v_cvt_pk_bf16_f32 %0, %1, %2" : "=v"(r) : "v"(a), "v"(b));
    return r;
}
__device__ __forceinline__ unsigned short f2bf(float f) {
    unsigned r;
    asm("v_cvt_pk_bf16_f32 %0, %1, %1" : "=v"(r) : "v"(f));
    return (unsigned short)r;
}
// raw v_exp_f32 (2^x); safe for finite x
__device__ __forceinline__ float exp2_raw(float x) {
    float r;
    asm("v_exp_f32 %0, %1" : "=v"(r) : "v"(x));
    return r;
}

__device__ __forceinline__ void glds16(const void* g, void* l) {
    __builtin_amdgcn_global_load_lds((__attribute__((address_space(1))) void*)(void*)g,
                                     (__attribute__((address_space(3))) void*)l, 16, 0, 0);
}

// ---------------- transpose f32 [R][C] -> bf16 [C][R] ----------------
__global__ __launch_bounds__(256) void transpose_to_bf16(
    const float* __restrict__ in, unsigned short* __restrict__ out, int R, int C) {
    __shared__ float tile[64][65];
    int n0 = blockIdx.x * 64, k0 = blockIdx.y * 64;
    int t = threadIdx.x;
#pragma unroll
    for (int i = 0; i < 16; i++) {
        int idx = i * 256 + t;
        int r = idx >> 6, c = idx & 63;
        tile[r][c] = in[(size_t)(k0 + r) * C + n0 + c];
    }
    __syncthreads();
#pragma unroll
    for (int i = 0; i < 16; i++) {
        int idx = i * 256 + t;
        int r = idx >> 6, c = idx & 63;
        out[(size_t)(n0 + r) * R + k0 + c] = f2bf(tile[c][r]);
    }
}

// ---------------- LayerNorm: f32 [8192][1024] -> bf16 ----------------
__global__ __launch_bounds__(256) void ln_kernel(
    const float* __restrict__ x, const float* __restrict__ gamma,
    const float* __restrict__ beta, unsigned short* __restrict__ xn) {
    int row = blockIdx.x;
    int t = threadIdx.x;
    const float4 v = ((const float4*)(x + (size_t)row * DIM))[t];
    float s = v.x + v.y + v.z + v.w;
    float sq = v.x * v.x + v.y * v.y + v.z * v.z + v.w * v.w;
#pragma unroll
    for (int m = 1; m < 64; m <<= 1) {
        s += __shfl_xor(s, m);
        sq += __shfl_xor(sq, m);
    }
    __shared__ float ws[4], wq[4];
    int w = t >> 6, lane = t & 63;
    if (lane == 0) { ws[w] = s; wq[w] = sq; }
    __syncthreads();
    s = ws[0] + ws[1] + ws[2] + ws[3];
    sq = wq[0] + wq[1] + wq[2] + wq[3];
    float mu = s * (1.0f / DIM);
    float var = sq * (1.0f / DIM) - mu * mu;
    float rstd = rsqrtf(var + 1e-5f);
    const float4 g = ((const float4*)gamma)[t];
    const float4 bb = ((const float4*)beta)[t];
    uint2 o;
    o.x = cvt2bf((v.x - mu) * rstd * g.x + bb.x, (v.y - mu) * rstd * g.y + bb.y);
    o.y = cvt2bf((v.z - mu) * rstd * g.z + bb.z, (v.w - mu) * rstd * g.w + bb.w);
    *(uint2*)(xn + (size_t)row * DIM + t * 4) = o;
}

// XCD-aware bijective swizzle of the linear workgroup id (nwg % 8 == 0)
__device__ __forceinline__ void xcd_swizzle(int& bx, int& by) {
    int nwgx = gridDim.x;
    int nwg = nwgx * gridDim.y;
    int wg = by * nwgx + bx;
    int cpx = nwg >> 3;
    int swz = (wg & 7) * cpx + (wg >> 3);
    bx = swz % nwgx;
    by = swz / nwgx;
}

// ---------------- shared GEMM core v4: 8 waves on 128x128 tile, 2x TLP ----------------
// C[128x128] = A[M,K] * Bt[N,K]^T. 512 threads = 8 waves (4M x 2N), wave = 64x32... no:
// wave wm=w>>1 (0..3) owns rows [wm*32,+32), wn=w&1 owns cols [wn*64,+64): acc[2][4].
// Round-11 COALESCED staging layout (lanes 0-3 cover one 64B row-segment; 16 segments
// per wave-load — round-12 lesson: global coalescing >> LDS bank conflicts).
// Counted-vmcnt 3-buffer pipeline: per K-step {vmcnt(2); s_barrier; stage(kt+2, 2 loads
// per wave); 6x ds_read_b128; 8 MFMA; rotate}. 48KB LDS -> 3 blocks/CU = 24 waves/CU
// (2x the 4-wave version — the latency-hiding lever this round).
// SPILL-FREE REQUIRED: scratch ops share vmcnt (v4 lesson); acc halved to 32 VGPR.
__device__ __forceinline__ void gemm_core8(
    const unsigned short* __restrict__ A, const unsigned short* __restrict__ Bt, int K,
    int brow, int bcol, char* As, char* Bs, f32x4 acc[2][4]) {
    int t = threadIdx.x, w = t >> 6, lane = t & 63;
    int wm = w >> 1, wn = w & 1;
    int srow = lane >> 2, scol = (lane & 3) * 8;
    // wave w stages A rows [w*16, +16) and B rows [w*16, +16) of the 128-row tiles
    const char* sA = (const char*)(A + (size_t)(brow + w * 16 + srow) * K + scol);
    const char* sB = (const char*)(Bt + (size_t)(bcol + w * 16 + srow) * K + scol);
    char* a0 = As; char* a1 = As + 8192; char* a2 = As + 16384;
    char* b0 = Bs; char* b1 = Bs + 8192; char* b2 = Bs + 16384;
    auto stage = [&](int k0, char* ab, char* bb) {
        glds16(sA + (size_t)k0 * 2, ab + w * 1024);
        glds16(sB + (size_t)k0 * 2, bb + w * 1024);
    };
    stage(0, a0, b0);
    stage(32, a1, b1);
    int NT = K >> 5;
    for (int kt = 0; kt < NT; kt++) {
        asm volatile("s_waitcnt vmcnt(2)" ::: "memory");  // tile kt's 2 loads landed (per-wave)
        __builtin_amdgcn_s_barrier();                     // all waves have tile kt; buf2 free
        int kn = kt + 2; if (kn >= NT) kn -= NT;          // wrap-reload at tail: harmless
        stage(kn << 5, a2, b2);
        bf16x8 a[2], b[4];
#pragma unroll
        for (int i = 0; i < 2; i++)
            a[i] = *(const bf16x8*)(a0 + (wm * 32 + i * 16 + (lane & 15)) * 64 + (lane >> 4) * 16);
#pragma unroll
        for (int j = 0; j < 4; j++)
            b[j] = *(const bf16x8*)(b0 + (wn * 64 + j * 16 + (lane & 15)) * 64 + (lane >> 4) * 16);
        __builtin_amdgcn_s_setprio(1);
#pragma unroll
        for (int i = 0; i < 2; i++)
#pragma unroll
            for (int j = 0; j < 4; j++)
                acc[i][j] = __builtin_amdgcn_mfma_f32_16x16x32_bf16(a[i], b[j], acc[i][j], 0, 0, 0);
        __builtin_amdgcn_s_setprio(0);
        char* tp;
        tp = a0; a0 = a1; a1 = a2; a2 = tp;
        tp = b0; b0 = b1; b1 = b2; b2 = tp;
    }
}

// QKV GEMM: xn[8192][1024] @ w_qkv -> writes Q (scaled), K, V^T in [b,h,...] layouts
#define QSCALE_LOG2E 0.18033688011112042f  // (1/sqrt(64)) * log2(e)

__global__ __launch_bounds__(512, 6) void gemm_qkv(
    const unsigned short* __restrict__ A, const unsigned short* __restrict__ Bt,
    unsigned short* __restrict__ Qb, unsigned short* __restrict__ Kb,
    unsigned short* __restrict__ Vt) {
    __shared__ __align__(16) char As[3 * 8192];
    __shared__ __align__(16) char Bs[3 * 8192];
    int bx = blockIdx.x, by = blockIdx.y;
    xcd_swizzle(bx, by);
    int brow = by * 128, bcol = bx * 128;
    f32x4 acc[2][4] = {};
    gemm_core8(A, Bt, DIM, brow, bcol, As, Bs, acc);

    int t = threadIdx.x, w = t >> 6, lane = t & 63;
    int wm = w >> 1, wn = w & 1;
    int part = bcol >> 10;  // uniform per block: 0=q 1=k 2=v
#pragma unroll
    for (int i = 0; i < 2; i++) {
#pragma unroll
        for (int j = 0; j < 4; j++) {
            int col = bcol + wn * 64 + j * 16 + (lane & 15);
            int within = col & 1023;
            int h = within >> 6, d = within & 63;
            int rowb = brow + wm * 32 + i * 16 + (lane >> 4) * 4;
            if (part == 2) {
                // V^T: n consecutive over r -> pack 4
                int b = rowb >> 11, n = rowb & 2047;
                int bh = (b << 4) + h;
                uint2 pv;
                pv.x = cvt2bf(acc[i][j][0], acc[i][j][1]);
                pv.y = cvt2bf(acc[i][j][2], acc[i][j][3]);
                *(uint2*)(Vt + ((size_t)bh * 64 + d) * 2048 + n) = pv;
            } else {
#pragma unroll
                for (int r = 0; r < 4; r++) {
                    int row = rowb + r;
                    int b = row >> 11, n = row & 2047;
                    int bh = (b << 4) + h;
                    float val = acc[i][j][r];
                    if (part == 0)
                        Qb[((size_t)bh * 2048 + n) * 64 + d] = f2bf(val * QSCALE_LOG2E);
                    else
                        Kb[((size_t)bh * 2048 + n) * 64 + d] = f2bf(val);
                }
            }
        }
    }
}

// out GEMM: att[8192][1024] @ w_out + b_out -> f32 out
__global__ __launch_bounds__(512, 6) void gemm_out(
    const unsigned short* __restrict__ A, const unsigned short* __restrict__ Bt,
    const float* __restrict__ bias, float* __restrict__ out) {
    __shared__ __align__(16) char As[3 * 8192];
    __shared__ __align__(16) char Bs[3 * 8192];
    int bx = blockIdx.x, by = blockIdx.y;
    xcd_swizzle(bx, by);
    int brow = by * 128, bcol = bx * 128;
    f32x4 acc[2][4] = {};
    gemm_core8(A, Bt, DIM, brow, bcol, As, Bs, acc);

    int t = threadIdx.x, w = t >> 6, lane = t & 63;
    int wm = w >> 1, wn = w & 1;
#pragma unroll
    for (int i = 0; i < 2; i++) {
#pragma unroll
        for (int j = 0; j < 4; j++) {
            int col = bcol + wn * 64 + j * 16 + (lane & 15);
            float bv = bias[col];
#pragma unroll
            for (int r = 0; r < 4; r++) {
                int row = brow + wm * 32 + i * 16 + (lane >> 4) * 4 + r;
                out[(size_t)row * DIM + col] = acc[i][j][r] + bv;
            }
        }
    }
}

// ---------------- flash attention v7: no-max softmax (round-11, unchanged) ----------------
__global__ __launch_bounds__(512, 4) void attn_kernel(
    const unsigned short* __restrict__ Qb, const unsigned short* __restrict__ Kb,
    const unsigned short* __restrict__ Vt, const float* __restrict__ pos,
    unsigned short* __restrict__ att) {
    __shared__ __align__(16) char Ks[4][8192];
    __shared__ __align__(16) char Vs[4][8192];
    int t = threadIdx.x, w = t >> 6, lane = t & 63;
    int l31 = lane & 31, lhi = lane >> 5;

    // XCD head-grouping: all q-tiles of head-batch bh land on XCD bh%8
    int L = blockIdx.y * gridDim.x + blockIdx.x;      // 0..511
    int bh = (L & 7) + (((L >> 3) & 7) << 3);         // head-batch index 0..63
    int qt = L >> 6;                                  // q-tile 0..7
    int b = bh >> 4, h = bh & 15;
    int qr = qt * 256 + w * 32 + l31;                 // this lane's q row

    const unsigned short* Qh = Qb + (size_t)bh * NSEQ * DH;
    const char* Khc = (const char*)(Kb + (size_t)bh * NSEQ * DH);
    const char* Vhc = (const char*)(Vt + (size_t)bh * DH * NSEQ);

    // Q fragments: qf[ks] = Q[qr][ks*16 + lhi*8 .. +8]
    bf16x8 qf[4];
#pragma unroll
    for (int ks = 0; ks < 4; ks++)
        qf[ks] = *(const bf16x8*)(Qh + (size_t)qr * DH + ks * 16 + lhi * 8);

    f32x16 oacc[2] = {};
    float lsum = 0.f;  // per-lane partial (pair-combined at epilogue)

    // fragment-ordered cooperative stage: wave w supplies chunk c=w (1 K + 1 V load)
    int ct = w >> 2, cs = w & 3;
    const char* Ksrc = Khc + (size_t)(ct * 32 + l31) * 128 + cs * 32 + lhi * 16;
    const char* Vsrc = Vhc + (size_t)(ct * 32 + l31) * 4096 + (size_t)(cs * 16 + lhi * 8) * 2;
    auto stage = [&](char* kbuf, char* vbuf, int kv0) {
        glds16(Ksrc + (size_t)kv0 * 128, kbuf + w * 1024);
        glds16(Vsrc + (size_t)kv0 * 2, vbuf + w * 1024);
    };

    // one KV-tile compute: QK^T -> P=exp2(S) -> PV
    auto compute = [&](const char* kc, const char* vc) {
        f32x16 st0 = {}, st1 = {};
        __builtin_amdgcn_s_setprio(1);
#pragma unroll
        for (int ks = 0; ks < 4; ks++) {
            bf16x8 kf = *(const bf16x8*)(kc + ks * 1024 + lane * 16);
            st0 = __builtin_amdgcn_mfma_f32_32x32x16_bf16(kf, qf[ks], st0, 0, 0, 0);
        }
#pragma unroll
        for (int ks = 0; ks < 4; ks++) {
            bf16x8 kf = *(const bf16x8*)(kc + (4 + ks) * 1024 + lane * 16);
            st1 = __builtin_amdgcn_mfma_f32_32x32x16_bf16(kf, qf[ks], st1, 0, 0, 0);
        }
        __builtin_amdgcn_s_setprio(0);

        // P = exp2(S) in place (no max subtraction); 4-way partial row-sum
        {
            float s0 = 0.f, s1 = 0.f, s2 = 0.f, s3 = 0.f;
#pragma unroll
            for (int r = 0; r < 16; r += 4) {
                float e0 = exp2_raw(st0[r]);
                float e1 = exp2_raw(st0[r + 1]);
                float e2 = exp2_raw(st0[r + 2]);
                float e3 = exp2_raw(st0[r + 3]);
                st0[r] = e0; st0[r + 1] = e1; st0[r + 2] = e2; st0[r + 3] = e3;
                s0 += e0; s1 += e1; s2 += e2; s3 += e3;
            }
#pragma unroll
            for (int r = 0; r < 16; r += 4) {
                float e0 = exp2_raw(st1[r]);
                float e1 = exp2_raw(st1[r + 1]);
                float e2 = exp2_raw(st1[r + 2]);
                float e3 = exp2_raw(st1[r + 3]);
                st1[r] = e0; st1[r + 1] = e1; st1[r + 2] = e2; st1[r + 3] = e3;
                s0 += e0; s1 += e1; s2 += e2; s3 += e3;
            }
            lsum += (s0 + s1) + (s2 + s3);
        }
        // build all 4 PV B-frags in-register (cvt_pk + permlane32_swap), then 8 PV MFMAs
        bf16x8 bfr[4];
#pragma unroll
        for (int ks = 0; ks < 4; ks++) {
            const f32x16& sv = (ks < 2) ? st0 : st1;
            int rb = (ks & 1) * 8;
            unsigned pa = cvt2bf(sv[rb + 0], sv[rb + 1]);
            unsigned pc = cvt2bf(sv[rb + 2], sv[rb + 3]);
            unsigned pb = cvt2bf(sv[rb + 4], sv[rb + 5]);
            unsigned pd = cvt2bf(sv[rb + 6], sv[rb + 7]);
            asm("v_permlane32_swap_b32 %0, %1" : "+v"(pa), "+v"(pb));
            asm("v_permlane32_swap_b32 %0, %1" : "+v"(pc), "+v"(pd));
            uint4 pw = {pa, pc, pb, pd};
            bfr[ks] = *(bf16x8*)&pw;
        }
        __builtin_amdgcn_s_setprio(1);
#pragma unroll
        for (int ks = 0; ks < 4; ks++)
#pragma unroll
            for (int dt = 0; dt < 2; dt++) {
                bf16x8 vf = *(const bf16x8*)(vc + (dt * 4 + ks) * 1024 + lane * 16);
                oacc[dt] = __builtin_amdgcn_mfma_f32_32x32x16_bf16(vf, bfr[ks], oacc[dt], 0, 0, 0);
            }
        __builtin_amdgcn_s_setprio(0);
    };

    char* kA0 = Ks[0]; char* kA1 = Ks[1]; char* kB0 = Ks[2]; char* kB1 = Ks[3];
    char* vA0 = Vs[0]; char* vA1 = Vs[1]; char* vB0 = Vs[2]; char* vB1 = Vs[3];
    stage(kA0, vA0, 0);
    stage(kA1, vA1, 64);

    for (int p = 0; p < 32; p += 2) {
        asm volatile("s_waitcnt vmcnt(2)" ::: "memory");  // tile p's K,V landed (per-wave)
        __builtin_amdgcn_s_barrier();                     // all waves have p; pair p-2 bufs free
        stage(kB0, vB0, ((p + 2) & 31) << 6);             // prefetch pair p+2 (wraps at end)
        stage(kB1, vB1, ((p + 3) & 31) << 6);
        compute(kA0, vA0);                                // tile p
        asm volatile("s_waitcnt vmcnt(4)" ::: "memory");  // tile p+1's K,V landed
        compute(kA1, vA1);                                // tile p+1 (no barrier needed)
        char* tp;
        tp = kA0; kA0 = kB0; kB0 = tp;  tp = kA1; kA1 = kB1; kB1 = tp;
        tp = vA0; vA0 = vB0; vB0 = tp;  tp = vA1; vA1 = vB1; vB1 = tp;
    }

    // epilogue: pair-combine lsum, then out[q][d] = oacc/lsum + pos, bf16
    {
        float pa = lsum, pb = lsum;
        asm("v_permlane32_swap_b32 %0, %1" : "+v"(pa), "+v"(pb));
        lsum = pa + pb;
    }
    float inv = 1.0f / lsum;
    size_t rowbase = ((size_t)b * NSEQ + qr) * DIM + h * 64;
#pragma unroll
    for (int dt = 0; dt < 2; dt++)
#pragma unroll
        for (int g4 = 0; g4 < 4; g4++) {
            int d = dt * 32 + g4 * 8 + lhi * 4;
            float4 pv = *(const float4*)(pos + rowbase + d);
            uint2 o;
            o.x = cvt2bf(oacc[dt][g4 * 4 + 0] * inv + pv.x, oacc[dt][g4 * 4 + 1] * inv + pv.y);
            o.y = cvt2bf(oacc[dt][g4 * 4 + 2] * inv + pv.z, oacc[dt][g4 * 4 + 3] * inv + pv.w);
            *(uint2*)(att + rowbase + d) = o;
        }
}

extern "C" void kernel_launch(void* const* d_in, const int* in_sizes, int n_in,
                              void* d_out, int out_size, void* d_ws, size_t ws_size,
                              hipStream_t stream) {
    const float* x = (const float*)d_in[0];
    const float* pos = (const float*)d_in[1];
    const float* w_qkv = (const float*)d_in[2];
    const float* w_out = (const float*)d_in[3];
    const float* b_out = (const float*)d_in[4];
    const float* ln_g = (const float*)d_in[5];
    const float* ln_b = (const float*)d_in[6];
    float* out = (float*)d_out;

    char* ws = (char*)d_ws;
    unsigned short* xn      = (unsigned short*)(ws);                       // 16MB (reused as att)
    unsigned short* wqkv_bt = (unsigned short*)(ws + (16ull << 20));       // 6MB
    unsigned short* wout_bt = (unsigned short*)(ws + (22ull << 20));       // 2MB
    unsigned short* Qb      = (unsigned short*)(ws + (24ull << 20));       // 16MB
    unsigned short* Kb      = (unsigned short*)(ws + (40ull << 20));       // 16MB
    unsigned short* Vt      = (unsigned short*)(ws + (56ull << 20));       // 16MB
    unsigned short* att     = xn;                                          // reuse

    transpose_to_bf16<<<dim3(N3 / 64, DIM / 64), 256, 0, stream>>>(w_qkv, wqkv_bt, DIM, N3);
    transpose_to_bf16<<<dim3(DIM / 64, DIM / 64), 256, 0, stream>>>(w_out, wout_bt, DIM, DIM);
    ln_kernel<<<TOKENS, 256, 0, stream>>>(x, ln_g, ln_b, xn);
    gemm_qkv<<<dim3(N3 / 128, TOKENS / 128), 512, 0, stream>>>(xn, wqkv_bt, Qb, Kb, Vt);
    attn_kernel<<<dim3(NSEQ / 256, 64), 512, 0, stream>>>(Qb, Kb, Vt, pos, att);
    gemm_out<<<dim3(DIM / 128, TOKENS / 128), 512, 0, stream>>>(att, wout_bt, b_out, out);
}